// Round 9
// baseline (159.096 us; speedup 1.0000x reference)
//
#include <hip/hip_runtime.h>

namespace {
constexpr int BLOCK = 256;
constexpr float WPF = 4.0f;
constexpr float LN2 = 0.69314718055994531f;
constexpr float LOG2E = 1.44269504088896340f;
// acc layout (ws, 14 floats): [0]=S13 (sum nltY-nlnY, t<4, log2 units)
// [1..4]=li_c (log2)  [5]=liN (log2)  [6..9]=cnt_c  [10..13]=nsel_c
// R6 lesson: never fuse finalize w/ per-block __threadfence (per-XCD L2
// writeback storm, +80us). Separate 1-block launch is ~3us.
}

__device__ __forceinline__ float wave_reduce(float v) {
#pragma unroll
    for (int o = 32; o > 0; o >>= 1) v += __shfl_down(v, o, 64);
    return v;
}

__global__ __launch_bounds__(BLOCK) void mpu_main(const float* __restrict__ x,
                                                  const int* __restrict__ t,
                                                  float* __restrict__ acc, int N) {
    __shared__ float red[BLOCK / 64][16];

    float S13 = 0.f, li0 = 0.f, li1 = 0.f, li2 = 0.f, li3 = 0.f, liN = 0.f;
    int c0 = 0, c1 = 0, c2 = 0, c3 = 0, n0 = 0, n1 = 0, n2 = 0, n3 = 0;

    // log2-domain; no max-subtraction (|x|<~6.5 for N(0,1): exp2-safe).
    auto process = [&](float x0, float x1, float x2, float x3, float x4, int tc) {
        const float y0 = x0 * LOG2E, y1 = x1 * LOG2E, y2 = x2 * LOG2E,
                    y3 = x3 * LOG2E, y4 = x4 * LOG2E;
        const float f0 = __builtin_amdgcn_exp2f(y0);
        const float f1 = __builtin_amdgcn_exp2f(y1);
        const float f2 = __builtin_amdgcn_exp2f(y2);
        const float f3 = __builtin_amdgcn_exp2f(y3);
        const float f4 = __builtin_amdgcn_exp2f(y4);
        const float s = ((f0 + f1) + (f2 + f3)) + f4;    // sum e^{x_i}
        const float L2 = __builtin_amdgcn_logf(s);       // log2(sum)
        const float thr = L2 - 1.0f;
        // "all p<=0.5" is ymax <= log2(s)-1 with unnormalized s (R5 bug).
        const float ymax = fmaxf(fmaxf(fmaxf(y0, y1), fmaxf(y2, y3)), y4);
        const float yt = (tc == 0) ? y0 : (tc == 1) ? y1 : (tc == 2) ? y2
                       : (tc == 3) ? y3 : y4;
        const float nltY = L2 - yt;                      // -log2(p_t)
        const float nlnY = L2 - y4;                      // -log2(p_neg)
        const bool sel = (yt > thr);                     // p_t > 0.5
        const bool alle = (ymax <= thr);                 // all p <= 0.5
        const bool tpos = (tc < 4);
        // risk1-risk3 collapses to (LN2/N)*sum_{t<4}(nltY-nlnY) = (y4-yt)
        S13 += tpos ? (y4 - yt) : 0.f;
        const float cv = sel ? nlnY * __builtin_amdgcn_exp2f(nltY) : 0.f;
        li0 += (tc == 0) ? cv : 0.f;
        li1 += (tc == 1) ? cv : 0.f;
        li2 += (tc == 2) ? cv : 0.f;
        li3 += (tc == 3) ? cv : 0.f;
        liN += (tc == 4 && alle) ? nlnY : 0.f;

        const unsigned long long b0 = __ballot(tc == 0);
        const unsigned long long b1 = __ballot(tc == 1);
        const unsigned long long b2 = __ballot(tc == 2);
        const unsigned long long b3 = __ballot(tc == 3);
        const unsigned long long bs = __ballot(sel);
        c0 += (int)__popcll(b0);
        c1 += (int)__popcll(b1);
        c2 += (int)__popcll(b2);
        c3 += (int)__popcll(b3);
        n0 += (int)__popcll(bs & b0);
        n1 += (int)__popcll(bs & b1);
        n2 += (int)__popcll(bs & b2);
        n3 += (int)__popcll(bs & b3);
    };

    // 4 rows/thread: 96 B burst, 2 device-generations -> load/compute interleave
    const int pid = blockIdx.x * BLOCK + threadIdx.x;
    const int nQuad = N >> 2;

    if (pid < nQuad) {
        const float4* xv = reinterpret_cast<const float4*>(x) + (size_t)pid * 5;
        const float4 v0 = xv[0], v1 = xv[1], v2 = xv[2], v3 = xv[3], v4 = xv[4];
        const int4 ta = reinterpret_cast<const int4*>(t)[pid];
        process(v0.x, v0.y, v0.z, v0.w, v1.x, ta.x);
        process(v1.y, v1.z, v1.w, v2.x, v2.y, ta.y);
        process(v2.z, v2.w, v3.x, v3.y, v3.z, ta.z);
        process(v3.w, v4.x, v4.y, v4.z, v4.w, ta.w);
    }
    // tail rows (N % 4): single lane; ballots correct under 1-lane exec
    if (blockIdx.x == 0 && threadIdx.x == 0) {
        for (int k = (N >> 2) << 2; k < N; ++k)
            process(x[k * 5 + 0], x[k * 5 + 1], x[k * 5 + 2], x[k * 5 + 3],
                    x[k * 5 + 4], t[k]);
    }

    const int wv = threadIdx.x >> 6, ln = threadIdx.x & 63;
    float fr[6] = {S13, li0, li1, li2, li3, liN};
#pragma unroll
    for (int j = 0; j < 6; ++j) {
        const float v = wave_reduce(fr[j]);
        if (ln == 0) red[wv][j] = v;
    }
    if (ln == 0) {   // counts are wave-uniform after ballot/popc
        red[wv][6] = (float)c0;   red[wv][7] = (float)c1;
        red[wv][8] = (float)c2;   red[wv][9] = (float)c3;
        red[wv][10] = (float)n0;  red[wv][11] = (float)n1;
        red[wv][12] = (float)n2;  red[wv][13] = (float)n3;
    }
    __syncthreads();
    if (threadIdx.x < 14) {
        const float v = red[0][threadIdx.x] + red[1][threadIdx.x] +
                        red[2][threadIdx.x] + red[3][threadIdx.x];
        atomicAdd(&acc[threadIdx.x], v);   // device-scope by default; no fence
    }
}

__global__ void mpu_final(const float* __restrict__ acc, float* __restrict__ out, int N) {
    if (threadIdx.x == 0 && blockIdx.x == 0) {
        const float invN = 1.0f / (float)N;
        // risk1 - risk3 collapses exactly: priors/denoms cancel; S13 in log2
        // units times LN2... S13 accumulated (y4-yt) = LOG2E*(x4-xt), so *LN2.
        const float risk13 = LN2 * acc[0] * invN;
        float risk2 = 0.0f;
#pragma unroll
        for (int c = 0; c < 4; ++c)
            risk2 += (acc[6 + c] * invN) *
                     (LN2 * acc[1 + c] / fmaxf(acc[10 + c], 1.0f));
        const float c4 = (float)N - (acc[6] + acc[7] + acc[8] + acc[9]);
        const float risk4 = LN2 * acc[5] / fmaxf(c4, 1.0f);
        float pos = WPF * (risk13 + risk2);
        if (pos < 0.0f) pos = 0.0f;
        out[0] = pos + risk4;
    }
}

extern "C" void kernel_launch(void* const* d_in, const int* in_sizes, int n_in,
                              void* d_out, int out_size, void* d_ws, size_t ws_size,
                              hipStream_t stream) {
    const float* x = (const float*)d_in[0];
    const int* t = (const int*)d_in[1];
    float* out = (float*)d_out;
    float* acc = (float*)d_ws;
    const int N = in_sizes[1];

    hipMemsetAsync(acc, 0, 64, stream);

    const int nQuad = N >> 2;
    int grid = (nQuad + BLOCK - 1) / BLOCK;
    if (grid < 1) grid = 1;
    mpu_main<<<grid, BLOCK, 0, stream>>>(x, t, acc, N);
    mpu_final<<<1, 64, 0, stream>>>(acc, out, N);
}

// Round 10
// 136.511 us; speedup vs baseline: 1.1654x; 1.1654x over previous
//
#include <hip/hip_runtime.h>

namespace {
constexpr int BLOCK = 256;
constexpr float WPF = 4.0f;
constexpr float LN2 = 0.69314718055994531f;
constexpr float LOG2E = 1.44269504088896340f;
// acc layout (ws, 14 floats): [0]=S13 (sum (y4-yt), t<4, log2 units)
// [1..4]=li_c (log2)  [5]=liN (log2)  [6..9]=cnt_c  [10..13]=nsel_c
// R6 lesson: never fuse finalize w/ per-block __threadfence (per-XCD L2
// writeback storm, +80us). Separate 1-block launch is ~3us.
// R9 lesson: compiler serializes "independent" loads to save VGPRs
// (VGPR_Count=20 with 24 regs of loads declared!). sched_barrier(0) after
// the load block forces all loads in flight -> real MLP.
}

__device__ __forceinline__ float wave_reduce(float v) {
#pragma unroll
    for (int o = 32; o > 0; o >>= 1) v += __shfl_down(v, o, 64);
    return v;
}

__global__ __launch_bounds__(BLOCK) void mpu_main(const float* __restrict__ x,
                                                  const int* __restrict__ t,
                                                  float* __restrict__ acc, int N) {
    __shared__ float red[BLOCK / 64][16];

    float S13 = 0.f, li0 = 0.f, li1 = 0.f, li2 = 0.f, li3 = 0.f, liN = 0.f;
    int c0 = 0, c1 = 0, c2 = 0, c3 = 0, n0 = 0, n1 = 0, n2 = 0, n3 = 0;

    // log2-domain; no max-subtraction (|x|<~6.5 for N(0,1): exp2-safe).
    auto process = [&](float x0, float x1, float x2, float x3, float x4, int tc) {
        const float y0 = x0 * LOG2E, y1 = x1 * LOG2E, y2 = x2 * LOG2E,
                    y3 = x3 * LOG2E, y4 = x4 * LOG2E;
        const float f0 = __builtin_amdgcn_exp2f(y0);
        const float f1 = __builtin_amdgcn_exp2f(y1);
        const float f2 = __builtin_amdgcn_exp2f(y2);
        const float f3 = __builtin_amdgcn_exp2f(y3);
        const float f4 = __builtin_amdgcn_exp2f(y4);
        const float s = ((f0 + f1) + (f2 + f3)) + f4;    // sum e^{x_i}
        const float L2 = __builtin_amdgcn_logf(s);       // log2(sum)
        const float thr = L2 - 1.0f;
        // "all p<=0.5" is ymax <= log2(s)-1 with unnormalized s (R5 bug).
        const float ymax = fmaxf(fmaxf(fmaxf(y0, y1), fmaxf(y2, y3)), y4);
        const float yt = (tc == 0) ? y0 : (tc == 1) ? y1 : (tc == 2) ? y2
                       : (tc == 3) ? y3 : y4;
        const float nltY = L2 - yt;                      // -log2(p_t)
        const float nlnY = L2 - y4;                      // -log2(p_neg)
        const bool sel = (yt > thr);                     // p_t > 0.5
        const bool alle = (ymax <= thr);                 // all p <= 0.5
        const bool tpos = (tc < 4);
        // risk1-risk3 collapses to (LN2/N)*sum_{t<4}(y4-yt)
        S13 += tpos ? (y4 - yt) : 0.f;
        const float cv = sel ? nlnY * __builtin_amdgcn_exp2f(nltY) : 0.f;
        li0 += (tc == 0) ? cv : 0.f;
        li1 += (tc == 1) ? cv : 0.f;
        li2 += (tc == 2) ? cv : 0.f;
        li3 += (tc == 3) ? cv : 0.f;
        liN += (tc == 4 && alle) ? nlnY : 0.f;

        const unsigned long long b0 = __ballot(tc == 0);
        const unsigned long long b1 = __ballot(tc == 1);
        const unsigned long long b2 = __ballot(tc == 2);
        const unsigned long long b3 = __ballot(tc == 3);
        const unsigned long long bs = __ballot(sel);
        c0 += (int)__popcll(b0);
        c1 += (int)__popcll(b1);
        c2 += (int)__popcll(b2);
        c3 += (int)__popcll(b3);
        n0 += (int)__popcll(bs & b0);
        n1 += (int)__popcll(bs & b1);
        n2 += (int)__popcll(bs & b2);
        n3 += (int)__popcll(bs & b3);
    };

    const int pid = blockIdx.x * BLOCK + threadIdx.x;    // one thread = 8 rows
    const int nOct = N >> 3;

    if (pid < nOct) {
        const float4* xv = reinterpret_cast<const float4*>(x) + (size_t)pid * 10;
        const int4* tv = reinterpret_cast<const int4*>(t) + (size_t)pid * 2;
        const float4 v0 = xv[0], v1 = xv[1], v2 = xv[2], v3 = xv[3], v4 = xv[4];
        const float4 v5 = xv[5], v6 = xv[6], v7 = xv[7], v8 = xv[8], v9 = xv[9];
        const int4 ta = tv[0], tb = tv[1];
        // Fence the scheduler: nothing crosses -> all 12 loads issue before
        // any compute consumes them (forces the registers live, real MLP).
        __builtin_amdgcn_sched_barrier(0);
        process(v0.x, v0.y, v0.z, v0.w, v1.x, ta.x);
        process(v1.y, v1.z, v1.w, v2.x, v2.y, ta.y);
        process(v2.z, v2.w, v3.x, v3.y, v3.z, ta.z);
        process(v3.w, v4.x, v4.y, v4.z, v4.w, ta.w);
        process(v5.x, v5.y, v5.z, v5.w, v6.x, tb.x);
        process(v6.y, v6.z, v6.w, v7.x, v7.y, tb.y);
        process(v7.z, v7.w, v8.x, v8.y, v8.z, tb.z);
        process(v8.w, v9.x, v9.y, v9.z, v9.w, tb.w);
    }
    // tail rows (N % 8): single lane; ballots correct under 1-lane exec
    if (blockIdx.x == 0 && threadIdx.x == 0) {
        for (int k = (N >> 3) << 3; k < N; ++k)
            process(x[k * 5 + 0], x[k * 5 + 1], x[k * 5 + 2], x[k * 5 + 3],
                    x[k * 5 + 4], t[k]);
    }

    const int wv = threadIdx.x >> 6, ln = threadIdx.x & 63;
    float fr[6] = {S13, li0, li1, li2, li3, liN};
#pragma unroll
    for (int j = 0; j < 6; ++j) {
        const float v = wave_reduce(fr[j]);
        if (ln == 0) red[wv][j] = v;
    }
    if (ln == 0) {   // counts are wave-uniform after ballot/popc
        red[wv][6] = (float)c0;   red[wv][7] = (float)c1;
        red[wv][8] = (float)c2;   red[wv][9] = (float)c3;
        red[wv][10] = (float)n0;  red[wv][11] = (float)n1;
        red[wv][12] = (float)n2;  red[wv][13] = (float)n3;
    }
    __syncthreads();
    if (threadIdx.x < 14) {
        const float v = red[0][threadIdx.x] + red[1][threadIdx.x] +
                        red[2][threadIdx.x] + red[3][threadIdx.x];
        atomicAdd(&acc[threadIdx.x], v);   // device-scope by default; no fence
    }
}

__global__ void mpu_final(const float* __restrict__ acc, float* __restrict__ out, int N) {
    if (threadIdx.x == 0 && blockIdx.x == 0) {
        const float invN = 1.0f / (float)N;
        // S13 accumulated (y4-yt) = LOG2E*(x4-xt) -> multiply by LN2.
        const float risk13 = LN2 * acc[0] * invN;
        float risk2 = 0.0f;
#pragma unroll
        for (int c = 0; c < 4; ++c)
            risk2 += (acc[6 + c] * invN) *
                     (LN2 * acc[1 + c] / fmaxf(acc[10 + c], 1.0f));
        const float c4 = (float)N - (acc[6] + acc[7] + acc[8] + acc[9]);
        const float risk4 = LN2 * acc[5] / fmaxf(c4, 1.0f);
        float pos = WPF * (risk13 + risk2);
        if (pos < 0.0f) pos = 0.0f;
        out[0] = pos + risk4;
    }
}

extern "C" void kernel_launch(void* const* d_in, const int* in_sizes, int n_in,
                              void* d_out, int out_size, void* d_ws, size_t ws_size,
                              hipStream_t stream) {
    const float* x = (const float*)d_in[0];
    const int* t = (const int*)d_in[1];
    float* out = (float*)d_out;
    float* acc = (float*)d_ws;
    const int N = in_sizes[1];

    hipMemsetAsync(acc, 0, 64, stream);

    const int nOct = N >> 3;
    int grid = (nOct + BLOCK - 1) / BLOCK;
    if (grid < 1) grid = 1;
    mpu_main<<<grid, BLOCK, 0, stream>>>(x, t, acc, N);
    mpu_final<<<1, 64, 0, stream>>>(acc, out, N);
}

// Round 11
// 134.061 us; speedup vs baseline: 1.1867x; 1.0183x over previous
//
#include <hip/hip_runtime.h>

namespace {
constexpr int BLOCK = 256;
constexpr int GRID = 1024;   // 4 blocks/CU persistent; N/4 quads / 262144 threads = 4 sweeps
constexpr float WPF = 4.0f;
constexpr float LN2 = 0.69314718055994531f;
constexpr float LOG2E = 1.44269504088896340f;
// acc layout (ws, 14 floats): [0]=S13 (sum (y4-yt), t<4, log2 units)
// [1..4]=li_c (log2)  [5]=liN (log2)  [6..9]=cnt_c  [10..13]=nsel_c
// R6 lesson: no per-block __threadfence finalize (per-XCD L2 writeback storm).
// R9 lesson: compiler sinks "independent" loads to save VGPRs; sched_barrier(0)
// after each load block forces them in flight.
// R10 lesson: one-shot kernels can't pipeline — need persistent grid + iterations.
}

struct Quad { float4 v0, v1, v2, v3, v4; int4 tt; };

__device__ __forceinline__ float wave_reduce(float v) {
#pragma unroll
    for (int o = 32; o > 0; o >>= 1) v += __shfl_down(v, o, 64);
    return v;
}

__global__ __launch_bounds__(BLOCK) void mpu_main(const float* __restrict__ x,
                                                  const int* __restrict__ t,
                                                  float* __restrict__ acc, int N) {
    __shared__ float red[BLOCK / 64][16];

    float S13 = 0.f, li0 = 0.f, li1 = 0.f, li2 = 0.f, li3 = 0.f, liN = 0.f;
    int c0 = 0, c1 = 0, c2 = 0, c3 = 0, n0 = 0, n1 = 0, n2 = 0, n3 = 0;

    // log2-domain; no max-subtraction (|x|<~6.5 for N(0,1): exp2-safe).
    auto process = [&](float x0, float x1, float x2, float x3, float x4, int tc) {
        const float y0 = x0 * LOG2E, y1 = x1 * LOG2E, y2 = x2 * LOG2E,
                    y3 = x3 * LOG2E, y4 = x4 * LOG2E;
        const float f0 = __builtin_amdgcn_exp2f(y0);
        const float f1 = __builtin_amdgcn_exp2f(y1);
        const float f2 = __builtin_amdgcn_exp2f(y2);
        const float f3 = __builtin_amdgcn_exp2f(y3);
        const float f4 = __builtin_amdgcn_exp2f(y4);
        const float s = ((f0 + f1) + (f2 + f3)) + f4;    // sum e^{x_i}
        const float L2 = __builtin_amdgcn_logf(s);       // log2(sum)
        const float thr = L2 - 1.0f;
        // "all p<=0.5" is ymax <= log2(s)-1 with unnormalized s (R5 bug).
        const float ymax = fmaxf(fmaxf(fmaxf(y0, y1), fmaxf(y2, y3)), y4);
        const float yt = (tc == 0) ? y0 : (tc == 1) ? y1 : (tc == 2) ? y2
                       : (tc == 3) ? y3 : y4;
        const float nltY = L2 - yt;                      // -log2(p_t)
        const float nlnY = L2 - y4;                      // -log2(p_neg)
        const bool sel = (yt > thr);                     // p_t > 0.5
        const bool alle = (ymax <= thr);                 // all p <= 0.5
        const bool tpos = (tc < 4);
        S13 += tpos ? (y4 - yt) : 0.f;                   // risk1-risk3 collapse
        const float cv = sel ? nlnY * __builtin_amdgcn_exp2f(nltY) : 0.f;
        li0 += (tc == 0) ? cv : 0.f;
        li1 += (tc == 1) ? cv : 0.f;
        li2 += (tc == 2) ? cv : 0.f;
        li3 += (tc == 3) ? cv : 0.f;
        liN += (tc == 4 && alle) ? nlnY : 0.f;

        const unsigned long long b0 = __ballot(tc == 0);
        const unsigned long long b1 = __ballot(tc == 1);
        const unsigned long long b2 = __ballot(tc == 2);
        const unsigned long long b3 = __ballot(tc == 3);
        const unsigned long long bs = __ballot(sel);
        c0 += (int)__popcll(b0);
        c1 += (int)__popcll(b1);
        c2 += (int)__popcll(b2);
        c3 += (int)__popcll(b3);
        n0 += (int)__popcll(bs & b0);
        n1 += (int)__popcll(bs & b1);
        n2 += (int)__popcll(bs & b2);
        n3 += (int)__popcll(bs & b3);
    };

    auto load_quad = [&](int g, Quad& q) {
        const float4* xv = reinterpret_cast<const float4*>(x) + (size_t)g * 5;
        q.v0 = xv[0]; q.v1 = xv[1]; q.v2 = xv[2]; q.v3 = xv[3]; q.v4 = xv[4];
        q.tt = reinterpret_cast<const int4*>(t)[g];
    };

    auto process4 = [&](const Quad& q) {
        process(q.v0.x, q.v0.y, q.v0.z, q.v0.w, q.v1.x, q.tt.x);
        process(q.v1.y, q.v1.z, q.v1.w, q.v2.x, q.v2.y, q.tt.y);
        process(q.v2.z, q.v2.w, q.v3.x, q.v3.y, q.v3.z, q.tt.z);
        process(q.v3.w, q.v4.x, q.v4.y, q.v4.z, q.v4.w, q.tt.w);
    };

    const int pid = blockIdx.x * BLOCK + threadIdx.x;
    const int S = gridDim.x * BLOCK;
    const int nQuad = N >> 2;
    const int niter = (nQuad + S - 1) / S;               // uniform across threads

    Quad A, B;
    if (pid < nQuad) load_quad(pid, A);
    for (int it = 0; it < niter; it += 2) {
        const int g1 = pid + (it + 1) * S;
        if (g1 < nQuad) load_quad(g1, B);                // prefetch next
        __builtin_amdgcn_sched_barrier(0);               // pin loads above compute
        const int gA = pid + it * S;
        if (gA < nQuad) process4(A);
        const int g2 = pid + (it + 2) * S;
        if (g2 < nQuad) load_quad(g2, A);                // prefetch next-next
        __builtin_amdgcn_sched_barrier(0);
        if (g1 < nQuad) process4(B);
    }

    // tail rows (N % 4): single lane; ballots correct under 1-lane exec
    if (blockIdx.x == 0 && threadIdx.x == 0) {
        for (int k = (N >> 2) << 2; k < N; ++k)
            process(x[k * 5 + 0], x[k * 5 + 1], x[k * 5 + 2], x[k * 5 + 3],
                    x[k * 5 + 4], t[k]);
    }

    const int wv = threadIdx.x >> 6, ln = threadIdx.x & 63;
    float fr[6] = {S13, li0, li1, li2, li3, liN};
#pragma unroll
    for (int j = 0; j < 6; ++j) {
        const float v = wave_reduce(fr[j]);
        if (ln == 0) red[wv][j] = v;
    }
    if (ln == 0) {   // counts are wave-uniform after ballot/popc
        red[wv][6] = (float)c0;   red[wv][7] = (float)c1;
        red[wv][8] = (float)c2;   red[wv][9] = (float)c3;
        red[wv][10] = (float)n0;  red[wv][11] = (float)n1;
        red[wv][12] = (float)n2;  red[wv][13] = (float)n3;
    }
    __syncthreads();
    if (threadIdx.x < 14) {
        const float v = red[0][threadIdx.x] + red[1][threadIdx.x] +
                        red[2][threadIdx.x] + red[3][threadIdx.x];
        atomicAdd(&acc[threadIdx.x], v);   // device-scope by default; no fence
    }
}

__global__ void mpu_final(const float* __restrict__ acc, float* __restrict__ out, int N) {
    if (threadIdx.x == 0 && blockIdx.x == 0) {
        const float invN = 1.0f / (float)N;
        // S13 accumulated (y4-yt) = LOG2E*(x4-xt) -> multiply by LN2.
        const float risk13 = LN2 * acc[0] * invN;
        float risk2 = 0.0f;
#pragma unroll
        for (int c = 0; c < 4; ++c)
            risk2 += (acc[6 + c] * invN) *
                     (LN2 * acc[1 + c] / fmaxf(acc[10 + c], 1.0f));
        const float c4 = (float)N - (acc[6] + acc[7] + acc[8] + acc[9]);
        const float risk4 = LN2 * acc[5] / fmaxf(c4, 1.0f);
        float pos = WPF * (risk13 + risk2);
        if (pos < 0.0f) pos = 0.0f;
        out[0] = pos + risk4;
    }
}

extern "C" void kernel_launch(void* const* d_in, const int* in_sizes, int n_in,
                              void* d_out, int out_size, void* d_ws, size_t ws_size,
                              hipStream_t stream) {
    const float* x = (const float*)d_in[0];
    const int* t = (const int*)d_in[1];
    float* out = (float*)d_out;
    float* acc = (float*)d_ws;
    const int N = in_sizes[1];

    hipMemsetAsync(acc, 0, 64, stream);

    const int nQuad = N >> 2;
    int grid = (nQuad + BLOCK - 1) / BLOCK;
    if (grid > GRID) grid = GRID;
    if (grid < 1) grid = 1;
    mpu_main<<<grid, BLOCK, 0, stream>>>(x, t, acc, N);
    mpu_final<<<1, 64, 0, stream>>>(acc, out, N);
}